// Round 2
// baseline (2041.780 us; speedup 1.0000x reference)
//
#include <hip/hip_runtime.h>
#include <math.h>

#define N_NODES 50000
#define N_EDGES 800000
#define FEAT    1024
#define OUT_C   256
#define HID     256
#define BATCH   2048

// ---------------------------------------------------------------------------
// CSR build: histogram -> single-block scan -> scatter
// ---------------------------------------------------------------------------
__global__ void hist_kernel(const int* __restrict__ row, int* __restrict__ cnt) {
    int i = blockIdx.x * blockDim.x + threadIdx.x;
    if (i < N_EDGES) atomicAdd(&cnt[row[i]], 1);
}

__global__ __launch_bounds__(1024)
void scan_kernel(const int* __restrict__ cnt, int* __restrict__ ptr) {
    const int PT = (N_NODES + 1023) / 1024;  // 49 rows per thread
    __shared__ int wsum[16];
    int t = threadIdx.x;
    int lane = t & 63, wid = t >> 6;
    int base = t * PT;
    int v[PT];
    int tot = 0;
#pragma unroll
    for (int j = 0; j < PT; ++j) {
        int r = base + j;
        v[j] = (r < N_NODES) ? cnt[r] : 0;
        tot += v[j];
    }
    // wave-inclusive scan of per-thread totals
    int x = tot;
#pragma unroll
    for (int d = 1; d < 64; d <<= 1) {
        int y = __shfl_up(x, d, 64);
        if (lane >= d) x += y;
    }
    if (lane == 63) wsum[wid] = x;
    __syncthreads();
    if (t == 0) {
        int run = 0;
        for (int w = 0; w < 16; ++w) { int s = wsum[w]; wsum[w] = run; run += s; }
        ptr[N_NODES] = run;  // == N_EDGES
    }
    __syncthreads();
    int excl = wsum[wid] + (x - tot);  // exclusive prefix of this thread
#pragma unroll
    for (int j = 0; j < PT; ++j) {
        int r = base + j;
        if (r < N_NODES) ptr[r] = excl;
        excl += v[j];
    }
}

__global__ void scatter_kernel(const int* __restrict__ row, const int* __restrict__ col,
                               const float* __restrict__ val, const int* __restrict__ ptr,
                               int* __restrict__ fill, int* __restrict__ ccol,
                               float* __restrict__ cval) {
    int e = blockIdx.x * blockDim.x + threadIdx.x;
    if (e < N_EDGES) {
        int r = row[e];
        int p = ptr[r] + atomicAdd(&fill[r], 1);
        ccol[p] = col[e];
        cval[p] = val[e];
    }
}

// ---------------------------------------------------------------------------
// SpMM (CSR gather): one wave per output row, lane l owns feats [4l, 4l+4)
// out[r][:] = (RELU?)( sum_e val[e]*dense[col[e]][:] + bias[:] )
// ---------------------------------------------------------------------------
template <bool RELU>
__global__ __launch_bounds__(256)
void spmm_kernel(const float* __restrict__ dense, const int* __restrict__ ptr,
                 const int* __restrict__ ccol, const float* __restrict__ cval,
                 const float* __restrict__ bias, float* __restrict__ out) {
    int wid = threadIdx.x >> 6;
    int lane = threadIdx.x & 63;
    int r = blockIdx.x * 4 + wid;
    if (r >= N_NODES) return;
    int beg = ptr[r], end = ptr[r + 1];
    float4 acc = make_float4(0.f, 0.f, 0.f, 0.f);
    int e = beg;
    for (; e + 1 < end; e += 2) {
        int c0 = ccol[e], c1 = ccol[e + 1];
        float v0 = cval[e], v1 = cval[e + 1];
        float4 d0 = *(const float4*)&dense[(size_t)c0 * OUT_C + lane * 4];
        float4 d1 = *(const float4*)&dense[(size_t)c1 * OUT_C + lane * 4];
        acc.x += v0 * d0.x + v1 * d1.x;
        acc.y += v0 * d0.y + v1 * d1.y;
        acc.z += v0 * d0.z + v1 * d1.z;
        acc.w += v0 * d0.w + v1 * d1.w;
    }
    if (e < end) {
        int c0 = ccol[e];
        float v0 = cval[e];
        float4 d0 = *(const float4*)&dense[(size_t)c0 * OUT_C + lane * 4];
        acc.x += v0 * d0.x; acc.y += v0 * d0.y; acc.z += v0 * d0.z; acc.w += v0 * d0.w;
    }
    float4 b = *(const float4*)&bias[lane * 4];
    acc.x += b.x; acc.y += b.y; acc.z += b.z; acc.w += b.w;
    if (RELU) {
        acc.x = fmaxf(acc.x, 0.f); acc.y = fmaxf(acc.y, 0.f);
        acc.z = fmaxf(acc.z, 0.f); acc.w = fmaxf(acc.w, 0.f);
    }
    *(float4*)&out[(size_t)r * OUT_C + lane * 4] = acc;
}

// ---------------------------------------------------------------------------
// fp32 NN GEMM: C[M,N] = A[M,K] @ B[K,N] (+bias). Tile 128x128xK8, 8x8/thread.
// ---------------------------------------------------------------------------
template <bool BIAS>
__global__ __launch_bounds__(256)
void gemm_nn(const float* __restrict__ A, const float* __restrict__ B,
             const float* __restrict__ bias, float* __restrict__ C,
             int M, int N, int K) {
    __shared__ float As[8][132];
    __shared__ float Bs[8][132];
    int tid = threadIdx.x;
    int tx = tid & 15, ty = tid >> 4;
    int bm = blockIdx.y * 128, bn = blockIdx.x * 128;

    int arow = tid >> 1;          // 0..127
    int acol = (tid & 1) << 2;    // 0 or 4
    int brow = tid >> 5;          // 0..7
    int bcol = (tid & 31) << 2;   // 0..124

    float acc[8][8] = {};

    for (int k0 = 0; k0 < K; k0 += 8) {
        float4 a4 = make_float4(0.f, 0.f, 0.f, 0.f);
        if (bm + arow < M) a4 = *(const float4*)&A[(size_t)(bm + arow) * K + k0 + acol];
        As[acol + 0][arow] = a4.x; As[acol + 1][arow] = a4.y;
        As[acol + 2][arow] = a4.z; As[acol + 3][arow] = a4.w;

        float4 b4 = make_float4(0.f, 0.f, 0.f, 0.f);
        if (bn + bcol < N) b4 = *(const float4*)&B[(size_t)(k0 + brow) * N + bn + bcol];
        *(float4*)&Bs[brow][bcol] = b4;
        __syncthreads();

#pragma unroll
        for (int kk = 0; kk < 8; ++kk) {
            float4 a0 = *(const float4*)&As[kk][ty * 8];
            float4 a1 = *(const float4*)&As[kk][ty * 8 + 4];
            float4 b0 = *(const float4*)&Bs[kk][tx * 8];
            float4 b1 = *(const float4*)&Bs[kk][tx * 8 + 4];
            float a[8] = {a0.x, a0.y, a0.z, a0.w, a1.x, a1.y, a1.z, a1.w};
            float b[8] = {b0.x, b0.y, b0.z, b0.w, b1.x, b1.y, b1.z, b1.w};
#pragma unroll
            for (int i = 0; i < 8; ++i)
#pragma unroll
                for (int j = 0; j < 8; ++j)
                    acc[i][j] = fmaf(a[i], b[j], acc[i][j]);
        }
        __syncthreads();
    }

    float bvals[8] = {};
    if (BIAS) {
#pragma unroll
        for (int j = 0; j < 8; ++j) {
            int c = bn + tx * 8 + j;
            bvals[j] = (c < N) ? bias[c] : 0.f;
        }
    }
#pragma unroll
    for (int i = 0; i < 8; ++i) {
        int r = bm + ty * 8 + i;
        if (r < M) {
            int c0 = bn + tx * 8;
            if (c0 < N) {
                float4 o = make_float4(acc[i][0] + bvals[0], acc[i][1] + bvals[1],
                                       acc[i][2] + bvals[2], acc[i][3] + bvals[3]);
                *(float4*)&C[(size_t)r * N + c0] = o;
            }
            if (c0 + 4 < N) {
                float4 o = make_float4(acc[i][4] + bvals[4], acc[i][5] + bvals[5],
                                       acc[i][6] + bvals[6], acc[i][7] + bvals[7]);
                *(float4*)&C[(size_t)r * N + c0 + 4] = o;
            }
        }
    }
}

// ---------------------------------------------------------------------------
// fp32 NT GEMM + sigmoid: C[M,N] = sigmoid(A[M,K] @ B[N,K]^T)
// ---------------------------------------------------------------------------
__global__ __launch_bounds__(256)
void gemm_nt_sigmoid(const float* __restrict__ A, const float* __restrict__ B,
                     float* __restrict__ C, int M, int N, int K) {
    __shared__ float As[8][132];
    __shared__ float Bs[8][132];
    int tid = threadIdx.x;
    int tx = tid & 15, ty = tid >> 4;
    int bm = blockIdx.y * 128, bn = blockIdx.x * 128;

    int arow = tid >> 1;          // 0..127
    int acol = (tid & 1) << 2;    // 0 or 4

    float acc[8][8] = {};

    for (int k0 = 0; k0 < K; k0 += 8) {
        float4 a4 = make_float4(0.f, 0.f, 0.f, 0.f);
        if (bm + arow < M) a4 = *(const float4*)&A[(size_t)(bm + arow) * K + k0 + acol];
        As[acol + 0][arow] = a4.x; As[acol + 1][arow] = a4.y;
        As[acol + 2][arow] = a4.z; As[acol + 3][arow] = a4.w;

        float4 b4 = make_float4(0.f, 0.f, 0.f, 0.f);
        if (bn + arow < N) b4 = *(const float4*)&B[(size_t)(bn + arow) * K + k0 + acol];
        Bs[acol + 0][arow] = b4.x; Bs[acol + 1][arow] = b4.y;
        Bs[acol + 2][arow] = b4.z; Bs[acol + 3][arow] = b4.w;
        __syncthreads();

#pragma unroll
        for (int kk = 0; kk < 8; ++kk) {
            float4 a0 = *(const float4*)&As[kk][ty * 8];
            float4 a1 = *(const float4*)&As[kk][ty * 8 + 4];
            float4 b0 = *(const float4*)&Bs[kk][tx * 8];
            float4 b1 = *(const float4*)&Bs[kk][tx * 8 + 4];
            float a[8] = {a0.x, a0.y, a0.z, a0.w, a1.x, a1.y, a1.z, a1.w};
            float b[8] = {b0.x, b0.y, b0.z, b0.w, b1.x, b1.y, b1.z, b1.w};
#pragma unroll
            for (int i = 0; i < 8; ++i)
#pragma unroll
                for (int j = 0; j < 8; ++j)
                    acc[i][j] = fmaf(a[i], b[j], acc[i][j]);
        }
        __syncthreads();
    }

#pragma unroll
    for (int i = 0; i < 8; ++i) {
        int r = bm + ty * 8 + i;
        if (r < M) {
            int c0 = bn + tx * 8;
            if (c0 < N) {
                float4 o;
                o.x = 1.f / (1.f + __expf(-acc[i][0]));
                o.y = 1.f / (1.f + __expf(-acc[i][1]));
                o.z = 1.f / (1.f + __expf(-acc[i][2]));
                o.w = 1.f / (1.f + __expf(-acc[i][3]));
                *(float4*)&C[(size_t)r * N + c0] = o;
            }
            if (c0 + 4 < N) {
                float4 o;
                o.x = 1.f / (1.f + __expf(-acc[i][4]));
                o.y = 1.f / (1.f + __expf(-acc[i][5]));
                o.z = 1.f / (1.f + __expf(-acc[i][6]));
                o.w = 1.f / (1.f + __expf(-acc[i][7]));
                *(float4*)&C[(size_t)r * N + c0 + 4] = o;
            }
        }
    }
}

// ---------------------------------------------------------------------------
extern "C" void kernel_launch(void* const* d_in, const int* in_sizes, int n_in,
                              void* d_out, int out_size, void* d_ws, size_t ws_size,
                              hipStream_t stream) {
    const float* x        = (const float*)d_in[0];
    const float* X        = (const float*)d_in[1];
    const float* W_comp   = (const float*)d_in[2];
    const float* b_comp   = (const float*)d_in[3];
    const float* W1       = (const float*)d_in[4];
    const float* b1       = (const float*)d_in[5];
    const float* W2       = (const float*)d_in[6];
    const float* b2       = (const float*)d_in[7];
    const float* edge_val = (const float*)d_in[8];
    const int*   edge_row = (const int*)d_in[9];
    const int*   edge_col = (const int*)d_in[10];
    float* out = (float*)d_out;

    char* w = (char*)d_ws;
    float* bufA = (float*)w;  w += (size_t)N_NODES * OUT_C * 4;   // 51.2 MB
    float* bufB = (float*)w;  w += (size_t)N_NODES * OUT_C * 4;   // 51.2 MB
    float* cval = (float*)w;  w += (size_t)N_EDGES * 4;           // 3.2 MB
    int*   ccol = (int*)w;    w += (size_t)N_EDGES * 4;           // 3.2 MB
    int*   rptr = (int*)w;    w += 200064;                        // 50001 ints
    int*   rcnt = (int*)w;    w += 200000;                        // 50000 ints
    int*   rfill = (int*)w;                                       // 50000 ints

    // zero histogram + fill cursors (adjacent, one memset covers both)
    hipMemsetAsync(rcnt, 0, 400000, stream);

    // CSR build
    hist_kernel<<<N_EDGES / 256, 256, 0, stream>>>(edge_row, rcnt);
    scan_kernel<<<1, 1024, 0, stream>>>(rcnt, rptr);
    scatter_kernel<<<N_EDGES / 256, 256, 0, stream>>>(edge_row, edge_col, edge_val,
                                                      rptr, rfill, ccol, cval);

    // f0 = X @ W_comp + b_comp            [50000,1024]x[1024,256] -> bufA
    gemm_nn<true><<<dim3(2, 391), 256, 0, stream>>>(X, W_comp, b_comp, bufA,
                                                    N_NODES, OUT_C, FEAT);
    // g1 = f0 @ W1                         -> bufB
    gemm_nn<false><<<dim3(2, 391), 256, 0, stream>>>(bufA, W1, nullptr, bufB,
                                                     N_NODES, HID, OUT_C);
    // f1 = relu(spmm(g1) + b1)             -> bufA
    spmm_kernel<true><<<N_NODES / 4, 256, 0, stream>>>(bufB, rptr, ccol, cval, b1, bufA);
    // g2 = f1 @ W2                         -> bufB
    gemm_nn<false><<<dim3(2, 391), 256, 0, stream>>>(bufA, W2, nullptr, bufB,
                                                     N_NODES, OUT_C, HID);
    // f2 = spmm(g2) + b2                   -> bufA
    spmm_kernel<false><<<N_NODES / 4, 256, 0, stream>>>(bufB, rptr, ccol, cval, b2, bufA);
    // out = sigmoid(x @ f2^T)              [2048,256]x[50000,256]^T -> d_out
    gemm_nt_sigmoid<<<dim3(391, 16), 256, 0, stream>>>(x, bufA, out,
                                                       BATCH, N_NODES, OUT_C);
}

// Round 3
// 1061.804 us; speedup vs baseline: 1.9229x; 1.9229x over previous
//
#include <hip/hip_runtime.h>
#include <math.h>

#define N_NODES 50000
#define N_EDGES 800000
#define FEAT    1024
#define OUT_C   256
#define HID     256
#define BATCH   2048

typedef _Float16 half_t;
typedef _Float16 half4_t __attribute__((ext_vector_type(4)));
typedef _Float16 half8_t __attribute__((ext_vector_type(8)));
typedef float f32x4 __attribute__((ext_vector_type(4)));

// ---------------------------------------------------------------------------
// CSR build: histogram -> single-block scan -> scatter (unchanged, verified)
// ---------------------------------------------------------------------------
__global__ void hist_kernel(const int* __restrict__ row, int* __restrict__ cnt) {
    int i = blockIdx.x * blockDim.x + threadIdx.x;
    if (i < N_EDGES) atomicAdd(&cnt[row[i]], 1);
}

__global__ __launch_bounds__(1024)
void scan_kernel(const int* __restrict__ cnt, int* __restrict__ ptr) {
    const int PT = (N_NODES + 1023) / 1024;
    __shared__ int wsum[16];
    int t = threadIdx.x;
    int lane = t & 63, wid = t >> 6;
    int base = t * PT;
    int v[PT];
    int tot = 0;
#pragma unroll
    for (int j = 0; j < PT; ++j) {
        int r = base + j;
        v[j] = (r < N_NODES) ? cnt[r] : 0;
        tot += v[j];
    }
    int x = tot;
#pragma unroll
    for (int d = 1; d < 64; d <<= 1) {
        int y = __shfl_up(x, d, 64);
        if (lane >= d) x += y;
    }
    if (lane == 63) wsum[wid] = x;
    __syncthreads();
    if (t == 0) {
        int run = 0;
        for (int w = 0; w < 16; ++w) { int s = wsum[w]; wsum[w] = run; run += s; }
        ptr[N_NODES] = run;
    }
    __syncthreads();
    int excl = wsum[wid] + (x - tot);
#pragma unroll
    for (int j = 0; j < PT; ++j) {
        int r = base + j;
        if (r < N_NODES) ptr[r] = excl;
        excl += v[j];
    }
}

__global__ void scatter_kernel(const int* __restrict__ row, const int* __restrict__ col,
                               const float* __restrict__ val, const int* __restrict__ ptr,
                               int* __restrict__ fill, int* __restrict__ ccol,
                               float* __restrict__ cval) {
    int e = blockIdx.x * blockDim.x + threadIdx.x;
    if (e < N_EDGES) {
        int r = row[e];
        int p = ptr[r] + atomicAdd(&fill[r], 1);
        ccol[p] = col[e];
        cval[p] = val[e];
    }
}

// ---------------------------------------------------------------------------
// transpose + fp32->fp16: out[c][r] = in[r][c]; in is [R][C]
// ---------------------------------------------------------------------------
__global__ void transpose_f16_kernel(const float* __restrict__ in, half_t* __restrict__ out,
                                     int R, int C) {
    int idx = blockIdx.x * 256 + threadIdx.x;
    if (idx < R * C) {
        int c = idx / R, r = idx - c * R;
        out[idx] = (half_t)in[r * C + c];
    }
}

// ---------------------------------------------------------------------------
// SpMM (CSR gather), fp16 dense/out, fp32 accum+bias.
// ---------------------------------------------------------------------------
template <bool RELU>
__global__ __launch_bounds__(256)
void spmm16_kernel(const half_t* __restrict__ dense, const int* __restrict__ ptr,
                   const int* __restrict__ ccol, const float* __restrict__ cval,
                   const float* __restrict__ bias, half_t* __restrict__ out) {
    int wid = threadIdx.x >> 6;
    int lane = threadIdx.x & 63;
    int r = blockIdx.x * 4 + wid;
    if (r >= N_NODES) return;
    int beg = ptr[r], end = ptr[r + 1];
    float ax = 0.f, ay = 0.f, az = 0.f, aw = 0.f;
    int e = beg;
    for (; e + 1 < end; e += 2) {
        int c0 = ccol[e], c1 = ccol[e + 1];
        float v0 = cval[e], v1 = cval[e + 1];
        half4_t d0 = *(const half4_t*)&dense[(size_t)c0 * OUT_C + lane * 4];
        half4_t d1 = *(const half4_t*)&dense[(size_t)c1 * OUT_C + lane * 4];
        ax += v0 * (float)d0.x + v1 * (float)d1.x;
        ay += v0 * (float)d0.y + v1 * (float)d1.y;
        az += v0 * (float)d0.z + v1 * (float)d1.z;
        aw += v0 * (float)d0.w + v1 * (float)d1.w;
    }
    if (e < end) {
        int c0 = ccol[e];
        float v0 = cval[e];
        half4_t d0 = *(const half4_t*)&dense[(size_t)c0 * OUT_C + lane * 4];
        ax += v0 * (float)d0.x; ay += v0 * (float)d0.y;
        az += v0 * (float)d0.z; aw += v0 * (float)d0.w;
    }
    float4 b = *(const float4*)&bias[lane * 4];
    ax += b.x; ay += b.y; az += b.z; aw += b.w;
    if (RELU) {
        ax = fmaxf(ax, 0.f); ay = fmaxf(ay, 0.f);
        az = fmaxf(az, 0.f); aw = fmaxf(aw, 0.f);
    }
    half4_t o; o.x = (half_t)ax; o.y = (half_t)ay; o.z = (half_t)az; o.w = (half_t)aw;
    *(half4_t*)&out[(size_t)r * OUT_C + lane * 4] = o;
}

// ---------------------------------------------------------------------------
// fp16 MFMA NT-GEMM: C[M,N] = A[M,K] @ Bt[N,K]^T  (+epilogue)
// Tile 128x128, BK=32, 4 waves (2x2), each wave 64x64 = 4x4 frags of 16x16.
//   A: lane l, elem j -> A[row = l&15][k = (l>>4)*8 + j]
//   B: lane l, elem j -> B[k = (l>>4)*8 + j][col = l&15]
//   D: lane l, reg  r -> C[row = (l>>4)*4 + r][col = l&15]   (m89/m91 verified)
// EPI: 0 = none (fp16 out), 1 = +bias (fp16 out), 2 = sigmoid (fp32 out)
// MORDER: true -> blockIdx.x is the M-block (m-fast order, B-strip L2 reuse)
// ---------------------------------------------------------------------------
template <typename AT, int EPI, bool MORDER>
__global__ __launch_bounds__(256)
void gemm_nt_f16(const AT* __restrict__ A, const half_t* __restrict__ Bt,
                 const float* __restrict__ bias, void* __restrict__ Cout,
                 int M, int N, int K) {
    __shared__ half_t As[128][48];   // row stride 96 B: 16B-aligned b128 reads
    __shared__ half_t Bs[128][48];

    const int tid = threadIdx.x;
    const int lane = tid & 63;
    const int w = tid >> 6;
    const int wr = w >> 1, wc = w & 1;
    const int bm = (MORDER ? blockIdx.x : blockIdx.y) * 128;
    const int bn = (MORDER ? blockIdx.y : blockIdx.x) * 128;

    f32x4 acc[4][4] = {};

    const int kd = (lane >> 4) * 8;
    const int fr = lane & 15;

    for (int k0 = 0; k0 < K; k0 += 32) {
        if constexpr (sizeof(AT) == 4) {
            int r = tid >> 1, cb = (tid & 1) * 16;
            int rr = bm + r; if (rr > M - 1) rr = M - 1;
            const float* src = A + (size_t)rr * K + k0 + cb;
#pragma unroll
            for (int q = 0; q < 4; ++q) {
                float4 v = *(const float4*)(src + 4 * q);
                half4_t h;
                h.x = (half_t)v.x; h.y = (half_t)v.y;
                h.z = (half_t)v.z; h.w = (half_t)v.w;
                *(half4_t*)&As[r][cb + 4 * q] = h;
            }
        } else {
#pragma unroll
            for (int q = 0; q < 2; ++q) {
                int c = tid + q * 256;
                int r = c >> 2, off = (c & 3) * 8;
                int rr = bm + r; if (rr > M - 1) rr = M - 1;
                half8_t v = *(const half8_t*)(A + (size_t)rr * K + k0 + off);
                *(half8_t*)&As[r][off] = v;
            }
        }
#pragma unroll
        for (int q = 0; q < 2; ++q) {
            int c = tid + q * 256;
            int r = c >> 2, off = (c & 3) * 8;
            int rr = bn + r; if (rr > N - 1) rr = N - 1;
            half8_t v = *(const half8_t*)(Bt + (size_t)rr * K + k0 + off);
            *(half8_t*)&Bs[r][off] = v;
        }
        __syncthreads();

        half8_t af[4], bf[4];
#pragma unroll
        for (int i = 0; i < 4; ++i)
            af[i] = *(const half8_t*)&As[wr * 64 + i * 16 + fr][kd];
#pragma unroll
        for (int j = 0; j < 4; ++j)
            bf[j] = *(const half8_t*)&Bs[wc * 64 + j * 16 + fr][kd];
#pragma unroll
        for (int i = 0; i < 4; ++i)
#pragma unroll
            for (int j = 0; j < 4; ++j)
                acc[i][j] = __builtin_amdgcn_mfma_f32_16x16x32_f16(af[i], bf[j], acc[i][j], 0, 0, 0);
        __syncthreads();
    }

    const int rowin = (lane >> 4) * 4;
    const int col = lane & 15;
#pragma unroll
    for (int i = 0; i < 4; ++i) {
#pragma unroll
        for (int j = 0; j < 4; ++j) {
            int cn = bn + wc * 64 + j * 16 + col;
            int rbase = bm + wr * 64 + i * 16 + rowin;
            if (cn >= N) continue;
            if constexpr (EPI == 2) {
                float* C = (float*)Cout;
#pragma unroll
                for (int r = 0; r < 4; ++r) {
                    int rm = rbase + r;
                    if (rm < M) C[(size_t)rm * N + cn] = 1.f / (1.f + __expf(-acc[i][j][r]));
                }
            } else {
                half_t* C = (half_t*)Cout;
                float bv = (EPI == 1) ? bias[cn] : 0.f;
#pragma unroll
                for (int r = 0; r < 4; ++r) {
                    int rm = rbase + r;
                    if (rm < M) C[(size_t)rm * N + cn] = (half_t)(acc[i][j][r] + bv);
                }
            }
        }
    }
}

// ---------------------------------------------------------------------------
extern "C" void kernel_launch(void* const* d_in, const int* in_sizes, int n_in,
                              void* d_out, int out_size, void* d_ws, size_t ws_size,
                              hipStream_t stream) {
    const float* x        = (const float*)d_in[0];
    const float* X        = (const float*)d_in[1];
    const float* W_comp   = (const float*)d_in[2];
    const float* b_comp   = (const float*)d_in[3];
    const float* W1       = (const float*)d_in[4];
    const float* b1       = (const float*)d_in[5];
    const float* W2       = (const float*)d_in[6];
    const float* b2       = (const float*)d_in[7];
    const float* edge_val = (const float*)d_in[8];
    const int*   edge_row = (const int*)d_in[9];
    const int*   edge_col = (const int*)d_in[10];
    float* out = (float*)d_out;

    char* w = (char*)d_ws;
    half_t* bufA16 = (half_t*)w;  w += (size_t)N_NODES * OUT_C * 2;
    half_t* bufB16 = (half_t*)w;  w += (size_t)N_NODES * OUT_C * 2;
    half_t* Wct    = (half_t*)w;  w += (size_t)OUT_C * FEAT * 2;
    half_t* W1t    = (half_t*)w;  w += (size_t)HID * OUT_C * 2;
    half_t* W2t    = (half_t*)w;  w += (size_t)OUT_C * HID * 2;
    float*  cval   = (float*)w;   w += (size_t)N_EDGES * 4;
    int*    ccol   = (int*)w;     w += (size_t)N_EDGES * 4;
    int*    rptr   = (int*)w;     w += 200064;
    int*    rcnt   = (int*)w;     w += 200000;
    int*    rfill  = (int*)w;

    hipMemsetAsync(rcnt, 0, 400000, stream);  // rcnt + adjacent rfill

    hist_kernel<<<N_EDGES / 256, 256, 0, stream>>>(edge_row, rcnt);
    scan_kernel<<<1, 1024, 0, stream>>>(rcnt, rptr);
    scatter_kernel<<<N_EDGES / 256, 256, 0, stream>>>(edge_row, edge_col, edge_val,
                                                      rptr, rfill, ccol, cval);

    transpose_f16_kernel<<<(FEAT * OUT_C + 255) / 256, 256, 0, stream>>>(W_comp, Wct, FEAT, OUT_C);
    transpose_f16_kernel<<<(OUT_C * HID + 255) / 256, 256, 0, stream>>>(W1, W1t, OUT_C, HID);
    transpose_f16_kernel<<<(HID * OUT_C + 255) / 256, 256, 0, stream>>>(W2, W2t, HID, OUT_C);

    // f0 = X @ W_comp + b_comp -> bufA16
    gemm_nt_f16<float, 1, false><<<dim3(2, 391), 256, 0, stream>>>(
        X, Wct, b_comp, bufA16, N_NODES, OUT_C, FEAT);
    // g1 = f0 @ W1 -> bufB16
    gemm_nt_f16<half_t, 0, false><<<dim3(2, 391), 256, 0, stream>>>(
        bufA16, W1t, nullptr, bufB16, N_NODES, HID, OUT_C);
    // f1 = relu(spmm(g1) + b1) -> bufA16
    spmm16_kernel<true><<<N_NODES / 4, 256, 0, stream>>>(bufB16, rptr, ccol, cval, b1, bufA16);
    // g2 = f1 @ W2 -> bufB16
    gemm_nt_f16<half_t, 0, false><<<dim3(2, 391), 256, 0, stream>>>(
        bufA16, W2t, nullptr, bufB16, N_NODES, OUT_C, HID);
    // f2 = spmm(g2) + b2 -> bufA16
    spmm16_kernel<false><<<N_NODES / 4, 256, 0, stream>>>(bufB16, rptr, ccol, cval, b2, bufA16);
    // out = sigmoid(x @ f2^T), m-fast block order for f2-strip L2 reuse
    gemm_nt_f16<float, 2, true><<<dim3(16, 391), 256, 0, stream>>>(
        x, bufA16, nullptr, out, BATCH, N_NODES, OUT_C);
}

// Round 4
// 1046.458 us; speedup vs baseline: 1.9511x; 1.0147x over previous
//
#include <hip/hip_runtime.h>
#include <math.h>

#define N_NODES 50000
#define N_EDGES 800000
#define FEAT    1024
#define OUT_C   256
#define HID     256
#define BATCH   2048

typedef _Float16 half_t;
typedef _Float16 half4_t __attribute__((ext_vector_type(4)));
typedef _Float16 half8_t __attribute__((ext_vector_type(8)));
typedef float f32x4 __attribute__((ext_vector_type(4)));

// ---------------------------------------------------------------------------
// CSR build: histogram -> single-block scan -> scatter (unchanged, verified)
// ---------------------------------------------------------------------------
__global__ void hist_kernel(const int* __restrict__ row, int* __restrict__ cnt) {
    int i = blockIdx.x * blockDim.x + threadIdx.x;
    if (i < N_EDGES) atomicAdd(&cnt[row[i]], 1);
}

__global__ __launch_bounds__(1024)
void scan_kernel(const int* __restrict__ cnt, int* __restrict__ ptr) {
    const int PT = (N_NODES + 1023) / 1024;
    __shared__ int wsum[16];
    int t = threadIdx.x;
    int lane = t & 63, wid = t >> 6;
    int base = t * PT;
    int v[PT];
    int tot = 0;
#pragma unroll
    for (int j = 0; j < PT; ++j) {
        int r = base + j;
        v[j] = (r < N_NODES) ? cnt[r] : 0;
        tot += v[j];
    }
    int x = tot;
#pragma unroll
    for (int d = 1; d < 64; d <<= 1) {
        int y = __shfl_up(x, d, 64);
        if (lane >= d) x += y;
    }
    if (lane == 63) wsum[wid] = x;
    __syncthreads();
    if (t == 0) {
        int run = 0;
        for (int w = 0; w < 16; ++w) { int s = wsum[w]; wsum[w] = run; run += s; }
        ptr[N_NODES] = run;
    }
    __syncthreads();
    int excl = wsum[wid] + (x - tot);
#pragma unroll
    for (int j = 0; j < PT; ++j) {
        int r = base + j;
        if (r < N_NODES) ptr[r] = excl;
        excl += v[j];
    }
}

__global__ void scatter_kernel(const int* __restrict__ row, const int* __restrict__ col,
                               const float* __restrict__ val, const int* __restrict__ ptr,
                               int* __restrict__ fill, int* __restrict__ ccol,
                               float* __restrict__ cval) {
    int e = blockIdx.x * blockDim.x + threadIdx.x;
    if (e < N_EDGES) {
        int r = row[e];
        int p = ptr[r] + atomicAdd(&fill[r], 1);
        ccol[p] = col[e];
        cval[p] = val[e];
    }
}

// ---------------------------------------------------------------------------
// transpose + fp32->fp16: out[c][r] = in[r][c]; in is [R][C]
// ---------------------------------------------------------------------------
__global__ void transpose_f16_kernel(const float* __restrict__ in, half_t* __restrict__ out,
                                     int R, int C) {
    int idx = blockIdx.x * 256 + threadIdx.x;
    if (idx < R * C) {
        int c = idx / R, r = idx - c * R;
        out[idx] = (half_t)in[r * C + c];
    }
}

// ---------------------------------------------------------------------------
// SpMM (CSR gather), fp16 dense/out, fp32 accum.
// One wave per row, split as 2 edge-groups x 32 lanes x half8 (16 B/lane).
// 4 edges in flight per main-loop iteration; __shfl_xor(32) merges groups.
// ---------------------------------------------------------------------------
template <bool RELU>
__global__ __launch_bounds__(256)
void spmm16_kernel(const half_t* __restrict__ dense, const int* __restrict__ ptr,
                   const int* __restrict__ ccol, const float* __restrict__ cval,
                   const float* __restrict__ bias, half_t* __restrict__ out) {
    int wid = threadIdx.x >> 6;
    int lane = threadIdx.x & 63;
    int g = lane >> 5;        // edge-group 0/1
    int sl = lane & 31;       // feat-lane: owns halves [sl*8, sl*8+8)
    int r = blockIdx.x * 4 + wid;
    if (r >= N_NODES) return;
    int beg = ptr[r], end = ptr[r + 1];
    float acc[8] = {};
    int e = beg;
    // 4 edges per iteration: group g handles e+g and e+g+2
    for (; e + 3 < end; e += 4) {
        int e0 = e + g, e1 = e + g + 2;
        int c0 = ccol[e0], c1 = ccol[e1];
        float v0 = cval[e0], v1 = cval[e1];
        half8_t d0 = *(const half8_t*)&dense[(size_t)c0 * OUT_C + sl * 8];
        half8_t d1 = *(const half8_t*)&dense[(size_t)c1 * OUT_C + sl * 8];
#pragma unroll
        for (int k = 0; k < 8; ++k)
            acc[k] += v0 * (float)d0[k] + v1 * (float)d1[k];
    }
    if (e + 1 < end) {  // 2-edge step
        int e0 = e + g;
        int c0 = ccol[e0];
        float v0 = cval[e0];
        half8_t d0 = *(const half8_t*)&dense[(size_t)c0 * OUT_C + sl * 8];
#pragma unroll
        for (int k = 0; k < 8; ++k) acc[k] += v0 * (float)d0[k];
        e += 2;
    }
    if (e < end) {  // single leftover edge: group 1 contributes zero weight
        int c0 = ccol[e];
        float v0 = g ? 0.f : cval[e];
        half8_t d0 = *(const half8_t*)&dense[(size_t)c0 * OUT_C + sl * 8];
#pragma unroll
        for (int k = 0; k < 8; ++k) acc[k] += v0 * (float)d0[k];
    }
    // merge the two edge-groups (lane l <-> l^32 hold the same feats)
#pragma unroll
    for (int k = 0; k < 8; ++k) acc[k] += __shfl_xor(acc[k], 32, 64);
    if (g == 0) {
        float4 b0 = *(const float4*)&bias[sl * 8];
        float4 b1 = *(const float4*)&bias[sl * 8 + 4];
        float bb[8] = {b0.x, b0.y, b0.z, b0.w, b1.x, b1.y, b1.z, b1.w};
        half8_t o;
#pragma unroll
        for (int k = 0; k < 8; ++k) {
            float v = acc[k] + bb[k];
            if (RELU) v = fmaxf(v, 0.f);
            o[k] = (half_t)v;
        }
        *(half8_t*)&out[(size_t)r * OUT_C + sl * 8] = o;
    }
}

// ---------------------------------------------------------------------------
// fp16 MFMA NT-GEMM: C[M,N] = A[M,K] @ Bt[N,K]^T  (+epilogue)
// Tile 128x128, BK=32, 4 waves (2x2), each wave 64x64 = 4x4 frags of 16x16.
//   A: lane l, elem j -> A[row = l&15][k = (l>>4)*8 + j]
//   B: lane l, elem j -> B[k = (l>>4)*8 + j][col = l&15]
//   D: lane l, reg  r -> C[row = (l>>4)*4 + r][col = l&15]   (m89/m91 verified)
// EPI: 0 = none (fp16 out), 1 = +bias (fp16 out), 2 = sigmoid (fp32 out)
// MORDER: true -> blockIdx.x is the M-block (m-fast order, B-strip L2 reuse)
// ---------------------------------------------------------------------------
template <typename AT, int EPI, bool MORDER>
__global__ __launch_bounds__(256)
void gemm_nt_f16(const AT* __restrict__ A, const half_t* __restrict__ Bt,
                 const float* __restrict__ bias, void* __restrict__ Cout,
                 int M, int N, int K) {
    __shared__ half_t As[128][48];   // row stride 96 B: 16B-aligned b128 reads
    __shared__ half_t Bs[128][48];

    const int tid = threadIdx.x;
    const int lane = tid & 63;
    const int w = tid >> 6;
    const int wr = w >> 1, wc = w & 1;
    const int bm = (MORDER ? blockIdx.x : blockIdx.y) * 128;
    const int bn = (MORDER ? blockIdx.y : blockIdx.x) * 128;

    f32x4 acc[4][4] = {};

    const int kd = (lane >> 4) * 8;
    const int fr = lane & 15;

    for (int k0 = 0; k0 < K; k0 += 32) {
        if constexpr (sizeof(AT) == 4) {
            int r = tid >> 1, cb = (tid & 1) * 16;
            int rr = bm + r; if (rr > M - 1) rr = M - 1;
            const float* src = A + (size_t)rr * K + k0 + cb;
#pragma unroll
            for (int q = 0; q < 4; ++q) {
                float4 v = *(const float4*)(src + 4 * q);
                half4_t h;
                h.x = (half_t)v.x; h.y = (half_t)v.y;
                h.z = (half_t)v.z; h.w = (half_t)v.w;
                *(half4_t*)&As[r][cb + 4 * q] = h;
            }
        } else {
#pragma unroll
            for (int q = 0; q < 2; ++q) {
                int c = tid + q * 256;
                int r = c >> 2, off = (c & 3) * 8;
                int rr = bm + r; if (rr > M - 1) rr = M - 1;
                half8_t v = *(const half8_t*)(A + (size_t)rr * K + k0 + off);
                *(half8_t*)&As[r][off] = v;
            }
        }
#pragma unroll
        for (int q = 0; q < 2; ++q) {
            int c = tid + q * 256;
            int r = c >> 2, off = (c & 3) * 8;
            int rr = bn + r; if (rr > N - 1) rr = N - 1;
            half8_t v = *(const half8_t*)(Bt + (size_t)rr * K + k0 + off);
            *(half8_t*)&Bs[r][off] = v;
        }
        __syncthreads();

        half8_t af[4], bf[4];
#pragma unroll
        for (int i = 0; i < 4; ++i)
            af[i] = *(const half8_t*)&As[wr * 64 + i * 16 + fr][kd];
#pragma unroll
        for (int j = 0; j < 4; ++j)
            bf[j] = *(const half8_t*)&Bs[wc * 64 + j * 16 + fr][kd];
#pragma unroll
        for (int i = 0; i < 4; ++i)
#pragma unroll
            for (int j = 0; j < 4; ++j)
                acc[i][j] = __builtin_amdgcn_mfma_f32_16x16x32_f16(af[i], bf[j], acc[i][j], 0, 0, 0);
        __syncthreads();
    }

    const int rowin = (lane >> 4) * 4;
    const int col = lane & 15;
#pragma unroll
    for (int i = 0; i < 4; ++i) {
#pragma unroll
        for (int j = 0; j < 4; ++j) {
            int cn = bn + wc * 64 + j * 16 + col;
            int rbase = bm + wr * 64 + i * 16 + rowin;
            if (cn >= N) continue;
            if constexpr (EPI == 2) {
                float* C = (float*)Cout;
#pragma unroll
                for (int r = 0; r < 4; ++r) {
                    int rm = rbase + r;
                    if (rm < M) C[(size_t)rm * N + cn] = 1.f / (1.f + __expf(-acc[i][j][r]));
                }
            } else {
                half_t* C = (half_t*)Cout;
                float bv = (EPI == 1) ? bias[cn] : 0.f;
#pragma unroll
                for (int r = 0; r < 4; ++r) {
                    int rm = rbase + r;
                    if (rm < M) C[(size_t)rm * N + cn] = (half_t)(acc[i][j][r] + bv);
                }
            }
        }
    }
}

// ---------------------------------------------------------------------------
extern "C" void kernel_launch(void* const* d_in, const int* in_sizes, int n_in,
                              void* d_out, int out_size, void* d_ws, size_t ws_size,
                              hipStream_t stream) {
    const float* x        = (const float*)d_in[0];
    const float* X        = (const float*)d_in[1];
    const float* W_comp   = (const float*)d_in[2];
    const float* b_comp   = (const float*)d_in[3];
    const float* W1       = (const float*)d_in[4];
    const float* b1       = (const float*)d_in[5];
    const float* W2       = (const float*)d_in[6];
    const float* b2       = (const float*)d_in[7];
    const float* edge_val = (const float*)d_in[8];
    const int*   edge_row = (const int*)d_in[9];
    const int*   edge_col = (const int*)d_in[10];
    float* out = (float*)d_out;

    char* w = (char*)d_ws;
    half_t* bufA16 = (half_t*)w;  w += (size_t)N_NODES * OUT_C * 2;
    half_t* bufB16 = (half_t*)w;  w += (size_t)N_NODES * OUT_C * 2;
    half_t* Wct    = (half_t*)w;  w += (size_t)OUT_C * FEAT * 2;
    half_t* W1t    = (half_t*)w;  w += (size_t)HID * OUT_C * 2;
    half_t* W2t    = (half_t*)w;  w += (size_t)OUT_C * HID * 2;
    float*  cval   = (float*)w;   w += (size_t)N_EDGES * 4;
    int*    ccol   = (int*)w;     w += (size_t)N_EDGES * 4;
    int*    rptr   = (int*)w;     w += 200064;
    int*    rcnt   = (int*)w;     w += 200000;
    int*    rfill  = (int*)w;

    hipMemsetAsync(rcnt, 0, 400000, stream);  // rcnt + adjacent rfill

    hist_kernel<<<N_EDGES / 256, 256, 0, stream>>>(edge_row, rcnt);
    scan_kernel<<<1, 1024, 0, stream>>>(rcnt, rptr);
    scatter_kernel<<<N_EDGES / 256, 256, 0, stream>>>(edge_row, edge_col, edge_val,
                                                      rptr, rfill, ccol, cval);

    transpose_f16_kernel<<<(FEAT * OUT_C + 255) / 256, 256, 0, stream>>>(W_comp, Wct, FEAT, OUT_C);
    transpose_f16_kernel<<<(OUT_C * HID + 255) / 256, 256, 0, stream>>>(W1, W1t, OUT_C, HID);
    transpose_f16_kernel<<<(HID * OUT_C + 255) / 256, 256, 0, stream>>>(W2, W2t, HID, OUT_C);

    // f0 = X @ W_comp + b_comp -> bufA16
    gemm_nt_f16<float, 1, false><<<dim3(2, 391), 256, 0, stream>>>(
        X, Wct, b_comp, bufA16, N_NODES, OUT_C, FEAT);
    // g1 = f0 @ W1 -> bufB16
    gemm_nt_f16<half_t, 0, false><<<dim3(2, 391), 256, 0, stream>>>(
        bufA16, W1t, nullptr, bufB16, N_NODES, HID, OUT_C);
    // f1 = relu(spmm(g1) + b1) -> bufA16
    spmm16_kernel<true><<<N_NODES / 4, 256, 0, stream>>>(bufB16, rptr, ccol, cval, b1, bufA16);
    // g2 = f1 @ W2 -> bufB16
    gemm_nt_f16<half_t, 0, false><<<dim3(2, 391), 256, 0, stream>>>(
        bufA16, W2t, nullptr, bufB16, N_NODES, OUT_C, HID);
    // f2 = spmm(g2) + b2 -> bufA16
    spmm16_kernel<false><<<N_NODES / 4, 256, 0, stream>>>(bufB16, rptr, ccol, cval, b2, bufA16);
    // out = sigmoid(x @ f2^T), m-fast block order for f2-strip L2 reuse
    gemm_nt_f16<float, 2, true><<<dim3(16, 391), 256, 0, stream>>>(
        x, bufA16, nullptr, out, BATCH, N_NODES, OUT_C);
}